// Round 11
// baseline (101.872 us; speedup 1.0000x reference)
//
#include <hip/hip_runtime.h>

// MixtureRouting: y[b,d,m] = sum_p x[b,d,p] * coef[b,p,m]
//   lh[b,p,m]  = pi[b,m] * prod_i( sig[b,i,m] / (PI*((mu[b,i,p]-mu[b,i,m])^2 + sig[b,i,m]^2)) )
//   coef[p,m]  = lh[p,m] / rowsum[p]
// R10 -> R11: gemm-side changes are invisible (R7==R10); remaining levers are dispatch
// count + prep-path traffic. Fuse rowsum+xbf into ONE kernel: block = (b, 16-p chunk)
// sweeps all 2048 m in 8 LDS-staged chunks, reduces rowsum locally (no rowsumPart
// global round-trip, no 25 MB of strided partial re-reads), then writes its
// xbf[b][d][p-chunk] slice. 2 dispatches total. gemm = R10's verified kernel.
// Diagnostic round: if total is unchanged (+-1.5us), the harness floor is confirmed.

typedef float v4f __attribute__((ext_vector_type(4)));
typedef float f32x4 __attribute__((ext_vector_type(4)));
typedef short bf16x8 __attribute__((ext_vector_type(8)));

namespace {
constexpr int BB = 4;
constexpr int DD = 81;
constexpr int KK = 2048;
constexpr int MROWS = 96;                 // padded d-rows for MFMA (6 tiles of 16)
constexpr float INV_PI4 = 1.0f / 97.40909103400243f;

// ws layout (bytes): only xbf now (1.57 MB)
constexpr size_t OFF_XBF = 0;                                     // ushort[B][96][K]
}

__device__ __forceinline__ unsigned short f2bf(float f) {
    union { float f; unsigned int u; } v; v.f = f;
    unsigned int u = v.u;
    unsigned int r = (u + 0x7FFFu + ((u >> 16) & 1u)) >> 16;   // RNE
    return (unsigned short)r;
}

// ---------------------------------------------------------------------------
// prep (fused rowsum + xbf): grid (KK/16, B) = 512 blocks, 256 threads.
// Block (b, p0 = 16-p chunk):
//   - sweep m = 0..2047 in 8 chunks of 256: stage m-side consts in LDS, each
//     thread (pl = t&15, mg = t>>4) evaluates lh[p0+pl, m] for its 16 m's/chunk,
//     accumulating a private partial rowsum
//   - 16-way LDS reduction -> invrow[16] (never leaves the block)
//   - xbf[b][d][p0+pl] = bf16(x[b][d][p0+pl] * invrow[pl]), 96 d-rows (81..95 zero)
// ---------------------------------------------------------------------------
__global__ __launch_bounds__(256) void prep_kernel(const float* __restrict__ x,
                                                   const float* __restrict__ pi_,
                                                   const float* __restrict__ mu,
                                                   const float* __restrict__ sig,
                                                   unsigned short* __restrict__ xbf) {
    __shared__ v4f   mush[256];          // 4 KB
    __shared__ v4f   s2sh[256];          // 4 KB
    __shared__ float csh[256];           // 1 KB
    __shared__ float sums[16][17];       // [mg][pl] (+1 pad)
    __shared__ float invr[16];

    int b  = blockIdx.y;
    int p0 = blockIdx.x * 16;
    int t  = threadIdx.x;
    int pl = t & 15;                     // p-lane
    int mg = t >> 4;                     // m-group 0..15

    const float* mub = mu  + (size_t)b * 4 * KK;
    const float* sgb = sig + (size_t)b * 4 * KK;
    const float* pib = pi_ + (size_t)b * KK;

    // p-side constants for this lane's p
    int p = p0 + pl;
    v4f mp = {mub[p], mub[KK + p], mub[2 * KK + p], mub[3 * KK + p]};

    float sum = 0.f;
    for (int c = 0; c < 8; ++c) {
        int m0 = c * 256;
        // stage this chunk's m-side constants (thread t -> m0+t, coalesced streams)
        {
            int m = m0 + t;
            v4f mm = {mub[m], mub[KK + m], mub[2 * KK + m], mub[3 * KK + m]};
            v4f sg = {sgb[m], sgb[KK + m], sgb[2 * KK + m], sgb[3 * KK + m]};
            mush[t] = mm;
            s2sh[t] = sg * sg;
            csh[t]  = pib[m] * ((sg.x * sg.y) * (sg.z * sg.w)) * INV_PI4;
        }
        __syncthreads();
#pragma unroll
        for (int j = 0; j < 16; ++j) {
            int mi = mg * 16 + j;        // this thread's m within the chunk
            v4f d = mp - mush[mi];
            v4f q = d * d + s2sh[mi];
            float den = (q.x * q.y) * (q.z * q.w);
            sum += csh[mi] * __builtin_amdgcn_rcpf(den);
        }
        __syncthreads();                 // protect stage buffers before next chunk
    }

    sums[mg][pl] = sum;
    __syncthreads();
    if (t < 16) {
        float s = 0.f;
#pragma unroll
        for (int g = 0; g < 16; ++g) s += sums[g][t];
        invr[t] = __builtin_amdgcn_rcpf(s);
    }
    __syncthreads();

    // xbf slice: 96 d-rows x 16 p. thread t -> p = p0+pl, d = mg + 16*k
    float ir = invr[pl];
    unsigned short* ob = xbf + ((size_t)b * MROWS) * KK + p0 + pl;
    const float* xb = x + ((size_t)b * DD) * KK + p0 + pl;
#pragma unroll
    for (int k = 0; k < 6; ++k) {
        int d = mg + 16 * k;             // 0..95
        float v = 0.f;
        if (d < DD) v = xb[(size_t)d * KK] * ir;
        ob[(size_t)d * KK] = f2bf(v);
    }
}

// ---------------------------------------------------------------------------
// gemm (fused lh): grid (128, B), 512 threads = 8 waves; __launch_bounds__(512,2)
// -> 2 blocks/CU (16 waves/CU). Block = (b, 16-col m-tile), full K=2048; wave w
// owns p-slice [w*256, w*256+256). A-frags prefetched; B-frags computed in regs
// from LDS-staged mu. A[m=lane&15][k=quad*8+j]; B[n=lane&15][k=quad*8+j];
// D col=lane&15,row=quad*4+reg. Epilogue: cross-wave LDS reduce + plain stores.
// ---------------------------------------------------------------------------
__global__ __launch_bounds__(512, 2) void gemm_kernel(const float* __restrict__ pi_,
                                                      const float* __restrict__ mu,
                                                      const float* __restrict__ sig,
                                                      const unsigned short* __restrict__ xbf,
                                                      float* __restrict__ out) {
    __shared__ __align__(16) char smem2[49152];
    v4f* mus = (v4f*)smem2;                             // [2048] 32 KB during K-loop
    f32x4 (*red)[6][64] = (f32x4 (*)[6][64])smem2;      // [8][6][64] 48 KB after barrier

    int t = threadIdx.x;
    int w = t >> 6, lane = t & 63;
    int r = lane & 15, q = lane >> 4;
    int b  = blockIdx.y;
    int m0 = blockIdx.x * 16;

    const float* mub = mu  + (size_t)b * 4 * KK;
    const float* sgb = sig + (size_t)b * 4 * KK;

    for (int i = t; i < KK; i += 512)
        mus[i] = (v4f){mub[i], mub[KK + i], mub[2 * KK + i], mub[3 * KK + i]};

    int m = m0 + r;
    v4f mm = {mub[m], mub[KK + m], mub[2 * KK + m], mub[3 * KK + m]};
    v4f sg = {sgb[m], sgb[KK + m], sgb[2 * KK + m], sgb[3 * KK + m]};
    v4f s2 = sg * sg;
    float cm = pi_[(size_t)b * KK + m] * ((sg.x * sg.y) * (sg.z * sg.w)) * INV_PI4;

    const unsigned short* Abase = xbf + ((size_t)(b * MROWS + r)) * KK;

    f32x4 acc[6];
#pragma unroll
    for (int i = 0; i < 6; ++i) acc[i] = (f32x4)0.f;

    __syncthreads();

    int pw = w * 256;

    // prefetch ks=0 A-fragments
    bf16x8 Af[6];
#pragma unroll
    for (int Mt = 0; Mt < 6; ++Mt)
        Af[Mt] = *(const bf16x8*)(Abase + (size_t)Mt * 16 * KK + pw + q * 8);

#pragma unroll
    for (int ks = 0; ks < 8; ++ks) {
        int pb = pw + ks * 32 + q * 8;

        // start next step's A-loads (overlap the Bf eval chain below)
        bf16x8 Afn[6];
        if (ks < 7) {
            int pbn = pb + 32;
#pragma unroll
            for (int Mt = 0; Mt < 6; ++Mt)
                Afn[Mt] = *(const bf16x8*)(Abase + (size_t)Mt * 16 * KK + pbn);
        }

        // build B fragment in registers: Bf[j] = bf16(lh[pb+j][m0+r])
        bf16x8 Bf;
#pragma unroll
        for (int j = 0; j < 8; ++j) {
            v4f mpv = mus[pb + j];
            v4f dd = mpv - mm;
            v4f qq = dd * dd + s2;
            float den = (qq.x * qq.y) * (qq.z * qq.w);
            float lh = cm * __builtin_amdgcn_rcpf(den);
            Bf[j] = (short)f2bf(lh);
        }

#pragma unroll
        for (int Mt = 0; Mt < 6; ++Mt)
            acc[Mt] = __builtin_amdgcn_mfma_f32_16x16x32_bf16(Af[Mt], Bf, acc[Mt], 0, 0, 0);

        if (ks < 7) {
#pragma unroll
            for (int Mt = 0; Mt < 6; ++Mt)
                Af[Mt] = Afn[Mt];
        }
    }

    __syncthreads();                                    // done reading mus
#pragma unroll
    for (int Mt = 0; Mt < 6; ++Mt)
        red[w][Mt][lane] = acc[Mt];
    __syncthreads();

    // 1536 outputs (96 rows x 16 cols) -> 3 per thread; skip d >= 81.
    int col = t & 15;
    int dr  = t >> 4;                                   // 0..31
#pragma unroll
    for (int k = 0; k < 3; ++k) {
        int d = dr + 32 * k;                            // 0..95
        if (d < DD) {
            int Mt  = d >> 4;
            int row = d & 15;
            int l   = (row >> 2) * 16 + col;
            int j   = row & 3;
            float s = 0.f;
#pragma unroll
            for (int ww = 0; ww < 8; ++ww) s += red[ww][Mt][l][j];
            out[((size_t)(b * DD + d)) * KK + m0 + col] = s;
        }
    }
}

extern "C" void kernel_launch(void* const* d_in, const int* in_sizes, int n_in,
                              void* d_out, int out_size, void* d_ws, size_t ws_size,
                              hipStream_t stream) {
    const float* x   = (const float*)d_in[0];
    const float* pi_ = (const float*)d_in[1];
    const float* mu  = (const float*)d_in[2];
    const float* sig = (const float*)d_in[3];
    float* out = (float*)d_out;

    unsigned short* xbf = (unsigned short*)((char*)d_ws + OFF_XBF);

    dim3 pg(KK / 16, BB);
    prep_kernel<<<pg, 256, 0, stream>>>(x, pi_, mu, sig, xbf);
    dim3 gg(KK / 16, BB);
    gemm_kernel<<<gg, 512, 0, stream>>>(pi_, mu, sig, xbf, out);
}